// Round 1
// baseline (1576.000 us; speedup 1.0000x reference)
//
#include <hip/hip_runtime.h>
#include <hip/hip_bf16.h>

#define D_IN   128
#define D_EDGE 32
#define D_OUT  128

// ---------------------------------------------------------------------------
// Kernel 1: fused node transform.
//   P[n,:]  = X[n,:] @ Wsrc           (message precompute, to workspace)
//   Hi[n,:] = X[n,:] @ Wl + bl        (self-loop init of the output)
// Block: 256 threads, 32 rows per block. Thread t owns column (t&127) for
// rows half*16..half*16+15 (half = t>>7). X tile staged in LDS (16 KB),
// read back as float4 broadcasts (wave-uniform address -> no bank conflict).
// ---------------------------------------------------------------------------
__global__ __launch_bounds__(256) void node_transform(
    const float* __restrict__ X,
    const float* __restrict__ Wsrc,
    const float* __restrict__ Wl,
    const float* __restrict__ bl,
    float* __restrict__ P,
    float* __restrict__ Hi,
    int N)
{
    __shared__ float Xs[32 * D_IN];
    const int tid  = threadIdx.x;
    const int row0 = blockIdx.x * 32;
    const int col  = tid & 127;
    const int half = tid >> 7;

    const int rows = min(32, N - row0);
    if (rows == 32) {
        const float4* X4  = (const float4*)(X + (size_t)row0 * D_IN);
        float4*       Xs4 = (float4*)Xs;
        #pragma unroll
        for (int j = 0; j < 4; ++j) Xs4[tid + j * 256] = X4[tid + j * 256];
    } else {
        for (int i = tid; i < rows * D_IN; i += 256)
            Xs[i] = X[(size_t)row0 * D_IN + i];
        for (int i = rows * D_IN + tid; i < 32 * D_IN; i += 256)
            Xs[i] = 0.f;
    }
    __syncthreads();

    float accP[16], accL[16];
    #pragma unroll
    for (int r = 0; r < 16; ++r) { accP[r] = 0.f; accL[r] = 0.f; }

    #pragma unroll 2
    for (int k0 = 0; k0 < D_IN; k0 += 4) {
        const float w0 = Wsrc[(k0 + 0) * D_OUT + col];
        const float w1 = Wsrc[(k0 + 1) * D_OUT + col];
        const float w2 = Wsrc[(k0 + 2) * D_OUT + col];
        const float w3 = Wsrc[(k0 + 3) * D_OUT + col];
        const float l0 = Wl[(k0 + 0) * D_OUT + col];
        const float l1 = Wl[(k0 + 1) * D_OUT + col];
        const float l2 = Wl[(k0 + 2) * D_OUT + col];
        const float l3 = Wl[(k0 + 3) * D_OUT + col];
        #pragma unroll
        for (int r = 0; r < 16; ++r) {
            const float4 x = *(const float4*)&Xs[(half * 16 + r) * D_IN + k0];
            accP[r] += x.x * w0 + x.y * w1 + x.z * w2 + x.w * w3;
            accL[r] += x.x * l0 + x.y * l1 + x.z * l2 + x.w * l3;
        }
    }

    const float blc = bl[col];
    #pragma unroll
    for (int r = 0; r < 16; ++r) {
        const int row = row0 + half * 16 + r;
        if (row < N) {
            P [(size_t)row * D_OUT + col] = accP[r];
            Hi[(size_t)row * D_OUT + col] = accL[r] + blc;
        }
    }
}

// ---------------------------------------------------------------------------
// Kernel 2: per-edge message + scatter (fast path, uses precomputed P).
// Each 128-thread group owns one edge; thread's col is FIXED for the whole
// kernel, so the needed W_edge column (32 floats) lives in registers.
//   msg[col] = relu(b[col] + P[src][col] + sum_k Xe[e][k]*We[k][col])
//   atomicAdd(H[dst][col], msg[col])
// ---------------------------------------------------------------------------
__global__ __launch_bounds__(256) void edge_scatter(
    const float* __restrict__ P,    // [Nsrc, D_OUT]
    const float* __restrict__ Xe,   // [E, D_EDGE]
    const float* __restrict__ We,   // [D_EDGE, D_OUT]
    const float* __restrict__ b,    // [D_OUT]
    const int*   __restrict__ src,
    const int*   __restrict__ dst,
    float*       __restrict__ H,    // [Ndst, D_OUT]
    int E)
{
    const int tid = threadIdx.x;
    const int col = tid & 127;
    const int sub = tid >> 7;

    float we[D_EDGE];
    #pragma unroll
    for (int k = 0; k < D_EDGE; ++k) we[k] = We[k * D_OUT + col];
    const float bc = b[col];

    const float4* Xe4 = (const float4*)Xe;
    const int slot   = blockIdx.x * 2 + sub;
    const int nslots = gridDim.x * 2;

    for (int e = slot; e < E; e += nslots) {
        const int s  = src[e];
        const int dt = dst[e];
        float acc = bc + P[(size_t)s * D_OUT + col];
        #pragma unroll
        for (int kk = 0; kk < 8; ++kk) {
            const float4 xv = Xe4[(size_t)e * 8 + kk];
            acc += xv.x * we[4 * kk + 0];
            acc += xv.y * we[4 * kk + 1];
            acc += xv.z * we[4 * kk + 2];
            acc += xv.w * we[4 * kk + 3];
        }
        acc = fmaxf(acc, 0.f);
        unsafeAtomicAdd(&H[(size_t)dt * D_OUT + col], acc);
    }
}

// ---------------------------------------------------------------------------
// Fallback (workspace too small for P tables): compute X[src]@Wsrc per edge,
// with Wsrc staged in LDS (64 KB).
// ---------------------------------------------------------------------------
__global__ __launch_bounds__(256) void edge_scatter_fused(
    const float* __restrict__ Xsrc,  // [Nsrc, D_IN]
    const float* __restrict__ Wsrc,  // [D_IN, D_OUT]
    const float* __restrict__ Xe,    // [E, D_EDGE]
    const float* __restrict__ We,    // [D_EDGE, D_OUT]
    const float* __restrict__ b,     // [D_OUT]
    const int*   __restrict__ src,
    const int*   __restrict__ dst,
    float*       __restrict__ H,     // [Ndst, D_OUT]
    int E)
{
    __shared__ float Ws[D_IN * D_OUT];  // 64 KB
    for (int i = threadIdx.x; i < D_IN * D_OUT; i += 256) Ws[i] = Wsrc[i];
    __syncthreads();

    const int tid = threadIdx.x;
    const int col = tid & 127;
    const int sub = tid >> 7;

    float we[D_EDGE];
    #pragma unroll
    for (int k = 0; k < D_EDGE; ++k) we[k] = We[k * D_OUT + col];
    const float bc = b[col];

    const float4* Xe4 = (const float4*)Xe;
    const int slot   = blockIdx.x * 2 + sub;
    const int nslots = gridDim.x * 2;

    for (int e = slot; e < E; e += nslots) {
        const int s  = src[e];
        const int dt = dst[e];
        float acc = bc;
        const float4* Xr4 = (const float4*)(Xsrc + (size_t)s * D_IN);
        #pragma unroll 8
        for (int k0 = 0; k0 < D_IN / 4; ++k0) {
            const float4 xv = Xr4[k0];
            acc += xv.x * Ws[(4 * k0 + 0) * D_OUT + col];
            acc += xv.y * Ws[(4 * k0 + 1) * D_OUT + col];
            acc += xv.z * Ws[(4 * k0 + 2) * D_OUT + col];
            acc += xv.w * Ws[(4 * k0 + 3) * D_OUT + col];
        }
        #pragma unroll
        for (int kk = 0; kk < 8; ++kk) {
            const float4 xv = Xe4[(size_t)e * 8 + kk];
            acc += xv.x * we[4 * kk + 0];
            acc += xv.y * we[4 * kk + 1];
            acc += xv.z * we[4 * kk + 2];
            acc += xv.w * we[4 * kk + 3];
        }
        acc = fmaxf(acc, 0.f);
        unsafeAtomicAdd(&H[(size_t)dt * D_OUT + col], acc);
    }
}

extern "C" void kernel_launch(void* const* d_in, const int* in_sizes, int n_in,
                              void* d_out, int out_size, void* d_ws, size_t ws_size,
                              hipStream_t stream)
{
    const float* X_user    = (const float*)d_in[0];
    const float* X_item    = (const float*)d_in[1];
    const float* Xe_ui     = (const float*)d_in[2];
    const float* Xe_iu     = (const float*)d_in[3];
    const float* W_src_ui  = (const float*)d_in[4];
    const float* W_edge_ui = (const float*)d_in[5];
    const float* b_ui      = (const float*)d_in[6];
    const float* W_src_iu  = (const float*)d_in[7];
    const float* W_edge_iu = (const float*)d_in[8];
    const float* b_iu      = (const float*)d_in[9];
    const float* Wl_user   = (const float*)d_in[10];
    const float* bl_user   = (const float*)d_in[11];
    const float* Wl_item   = (const float*)d_in[12];
    const float* bl_item   = (const float*)d_in[13];
    const int*   src_ui    = (const int*)d_in[14];
    const int*   dst_ui    = (const int*)d_in[15];
    const int*   src_iu    = (const int*)d_in[16];
    const int*   dst_iu    = (const int*)d_in[17];

    const int N_user = in_sizes[0] / D_IN;
    const int N_item = in_sizes[1] / D_IN;
    const int E      = in_sizes[14];

    float* H_user = (float*)d_out;                       // [N_user, 128]
    float* H_item = H_user + (size_t)N_user * D_OUT;     // [N_item, 128]

    const size_t needP = ((size_t)N_user + (size_t)N_item) * D_OUT * sizeof(float);
    const bool   useP  = (ws_size >= needP);

    float* P_user = (float*)d_ws;
    float* P_item = P_user + (size_t)N_user * D_OUT;

    const int ngrid_u = (N_user + 31) / 32;
    const int ngrid_i = (N_item + 31) / 32;
    const int eblocks = 8192;

    if (useP) {
        // P_user = X_user @ W_src_ui ; H_user = X_user @ Wl_user + bl_user
        node_transform<<<ngrid_u, 256, 0, stream>>>(
            X_user, W_src_ui, Wl_user, bl_user, P_user, H_user, N_user);
        // P_item = X_item @ W_src_iu ; H_item = X_item @ Wl_item + bl_item
        node_transform<<<ngrid_i, 256, 0, stream>>>(
            X_item, W_src_iu, Wl_item, bl_item, P_item, H_item, N_item);
        // relation user->item accumulates into H_item
        edge_scatter<<<eblocks, 256, 0, stream>>>(
            P_user, Xe_ui, W_edge_ui, b_ui, src_ui, dst_ui, H_item, E);
        // relation item->user accumulates into H_user
        edge_scatter<<<eblocks, 256, 0, stream>>>(
            P_item, Xe_iu, W_edge_iu, b_iu, src_iu, dst_iu, H_user, E);
    } else {
        // No workspace: still need H inits; reuse node_transform with P->ws
        // replaced by a dummy (write Hi only is not separable, so point P at
        // H temporarily is wrong; instead recompute per edge).
        // Write self-loop inits via node_transform with P = Hi trick avoided:
        // use a tiny variant: P target = H (overwritten later is WRONG), so
        // just run node_transform with P pointing at d_ws if any, else
        // compute Hi with the same kernel writing P into Hi twice.
        // Simplest correct: node_transform writing P into the FIRST half of
        // ws if it fits one table, else fall back to Hi-only behavior by
        // passing P==Hi and Wsrc==Wl (P result then overwritten by correct Hi).
        node_transform<<<ngrid_u, 256, 0, stream>>>(
            X_user, Wl_user, Wl_user, bl_user, H_user, H_user, N_user);
        node_transform<<<ngrid_i, 256, 0, stream>>>(
            X_item, Wl_item, Wl_item, bl_item, H_item, H_item, N_item);
        edge_scatter_fused<<<eblocks, 256, 0, stream>>>(
            X_user, W_src_ui, Xe_ui, W_edge_ui, b_ui, src_ui, dst_ui, H_item, E);
        edge_scatter_fused<<<eblocks, 256, 0, stream>>>(
            X_item, W_src_iu, Xe_iu, W_edge_iu, b_iu, src_iu, dst_iu, H_user, E);
    }
}

// Round 4
// 1201.521 us; speedup vs baseline: 1.3117x; 1.3117x over previous
//
#include <hip/hip_runtime.h>
#include <hip/hip_bf16.h>

#define D_IN   128
#define D_EDGE 32
#define D_OUT  128

// ---------------------------------------------------------------------------
// Kernel 1: fused node transform (64 rows per block).
//   P[n,:]  = X[n,:] @ Wsrc           (message precompute, to workspace)
//   Hi[n,:] = X[n,:] @ Wl + bl        (self-loop init of the output)
// 256 threads: thread t owns column (t&127) for rows q*32..q*32+31 (q=t>>7).
// X tile in LDS (32 KB); weight loads amortized over 32 rows per k-step.
// ---------------------------------------------------------------------------
__global__ __launch_bounds__(256) void node_transform(
    const float* __restrict__ X,
    const float* __restrict__ Wsrc,
    const float* __restrict__ Wl,
    const float* __restrict__ bl,
    float* __restrict__ P,
    float* __restrict__ Hi,
    int N)
{
    __shared__ float Xs[64 * D_IN];  // 32 KB
    const int tid  = threadIdx.x;
    const int row0 = blockIdx.x * 64;
    const int col  = tid & 127;
    const int q    = tid >> 7;       // wave-uniform (waves 0-1: q=0, 2-3: q=1)

    const int rows = min(64, N - row0);
    if (rows == 64) {
        const float4* X4  = (const float4*)(X + (size_t)row0 * D_IN);
        float4*       Xs4 = (float4*)Xs;
        #pragma unroll
        for (int j = 0; j < 8; ++j) Xs4[tid + j * 256] = X4[tid + j * 256];
    } else {
        for (int i = tid; i < rows * D_IN; i += 256)
            Xs[i] = X[(size_t)row0 * D_IN + i];
        for (int i = rows * D_IN + tid; i < 64 * D_IN; i += 256)
            Xs[i] = 0.f;
    }
    __syncthreads();

    float accP[32], accL[32];
    #pragma unroll
    for (int r = 0; r < 32; ++r) { accP[r] = 0.f; accL[r] = 0.f; }

    for (int k0 = 0; k0 < D_IN; k0 += 4) {
        const float w0 = Wsrc[(k0 + 0) * D_OUT + col];
        const float w1 = Wsrc[(k0 + 1) * D_OUT + col];
        const float w2 = Wsrc[(k0 + 2) * D_OUT + col];
        const float w3 = Wsrc[(k0 + 3) * D_OUT + col];
        const float l0 = Wl[(k0 + 0) * D_OUT + col];
        const float l1 = Wl[(k0 + 1) * D_OUT + col];
        const float l2 = Wl[(k0 + 2) * D_OUT + col];
        const float l3 = Wl[(k0 + 3) * D_OUT + col];
        #pragma unroll
        for (int r = 0; r < 32; ++r) {
            const float4 x = *(const float4*)&Xs[(q * 32 + r) * D_IN + k0];
            accP[r] += x.x * w0 + x.y * w1 + x.z * w2 + x.w * w3;
            accL[r] += x.x * l0 + x.y * l1 + x.z * l2 + x.w * l3;
        }
    }

    const float blc = bl[col];
    #pragma unroll
    for (int r = 0; r < 32; ++r) {
        const int row = row0 + q * 32 + r;
        if (row < N) {
            P [(size_t)row * D_OUT + col] = accP[r];
            Hi[(size_t)row * D_OUT + col] = accL[r] + blc;
        }
    }
}

// ---------------------------------------------------------------------------
// Counting sort of edges by dst: histogram -> chunked exclusive scan -> place.
// ---------------------------------------------------------------------------
__global__ __launch_bounds__(256) void hist2(
    const int* __restrict__ dst_a, const int* __restrict__ dst_b,
    int* __restrict__ cnt_a, int* __restrict__ cnt_b, int E)
{
    const int i = blockIdx.x * 256 + threadIdx.x;
    const int n = gridDim.x * 256;
    for (int e = i; e < E; e += n) atomicAdd(&cnt_a[dst_a[e]], 1);
    for (int e = i; e < E; e += n) atomicAdd(&cnt_b[dst_b[e]], 1);
}

// Per-256-chunk exclusive scan; block total to bsum.
__global__ __launch_bounds__(256) void scan1(
    const int* __restrict__ cnt, int* __restrict__ offs,
    int* __restrict__ bsum, int N)
{
    __shared__ int s[256];
    const int i = blockIdx.x * 256 + threadIdx.x;
    const int v = (i < N) ? cnt[i] : 0;
    s[threadIdx.x] = v;
    __syncthreads();
    for (int d = 1; d < 256; d <<= 1) {
        const int t = (threadIdx.x >= d) ? s[threadIdx.x - d] : 0;
        __syncthreads();
        s[threadIdx.x] += t;
        __syncthreads();
    }
    const int incl = s[threadIdx.x];
    if (i < N) offs[i] = incl - v;                 // exclusive within chunk
    if (threadIdx.x == 255) bsum[blockIdx.x] = incl;
}

// Exclusive scan of chunk totals (nch <= 512); also writes offs[N] = E.
__global__ __launch_bounds__(512) void scan2(
    int* __restrict__ bsum, int* __restrict__ offs, int N, int nch, int E)
{
    __shared__ int s[512];
    const int v = (threadIdx.x < nch) ? bsum[threadIdx.x] : 0;
    s[threadIdx.x] = v;
    __syncthreads();
    for (int d = 1; d < 512; d <<= 1) {
        const int t = (threadIdx.x >= d) ? s[threadIdx.x - d] : 0;
        __syncthreads();
        s[threadIdx.x] += t;
        __syncthreads();
    }
    if (threadIdx.x < nch) bsum[threadIdx.x] = s[threadIdx.x] - v;
    if (threadIdx.x == 0) offs[N] = E;
}

__global__ __launch_bounds__(256) void scan3(
    int* __restrict__ offs, const int* __restrict__ bsum, int N)
{
    const int i = blockIdx.x * 256 + threadIdx.x;
    if (i < N) offs[i] += bsum[blockIdx.x];
}

// Place edge ids into dst-sorted order (backward fill via atomicSub on counts).
__global__ __launch_bounds__(256) void scatter_sort(
    const int* __restrict__ dst, const int* __restrict__ offs,
    int* __restrict__ cnt, int* __restrict__ sorted, int E)
{
    const int i = blockIdx.x * 256 + threadIdx.x;
    const int n = gridDim.x * 256;
    for (int e = i; e < E; e += n) {
        const int d   = dst[e];
        const int old = atomicSub(&cnt[d], 1);
        sorted[offs[d] + old - 1] = e;
    }
}

// ---------------------------------------------------------------------------
// Kernel 2: atomic-free aggregation. One 128-thread block per dst node.
//   H[n,:] += sum_{e in edges(n)} relu(b + P[src[e],:] + Xe[e,:] @ We)
// eids/srcs for up to 128 edges prefetched wave-parallel into LDS (breaks the
// serial eid->src->P dependency chain); one plain RMW of the H row at the end.
// ---------------------------------------------------------------------------
__global__ __launch_bounds__(128) void aggregate(
    const float* __restrict__ P,      // [Nsrc, D_OUT]
    const float* __restrict__ Xe,     // [E, D_EDGE]
    const float* __restrict__ We,     // [D_EDGE, D_OUT]
    const float* __restrict__ b,      // [D_OUT]
    const int*   __restrict__ src,
    const int*   __restrict__ sorted, // [E] edge ids sorted by dst
    const int*   __restrict__ offs,   // [Ndst+1]
    float*       __restrict__ H,      // [Ndst, D_OUT]
    int N)
{
    const int n   = blockIdx.x;
    const int off = offs[n];
    const int deg = offs[n + 1] - off;
    if (deg == 0) return;

    const int col = threadIdx.x;
    float we[D_EDGE];
    #pragma unroll
    for (int k = 0; k < D_EDGE; ++k) we[k] = We[k * D_OUT + col];
    const float bc = b[col];

    __shared__ int eids[128];
    __shared__ int srcs[128];

    float acc = 0.f;
    for (int base = 0; base < deg; base += 128) {
        const int m = min(128, deg - base);
        if (col < m) eids[col] = sorted[off + base + col];
        __syncthreads();
        if (col < m) srcs[col] = src[eids[col]];
        __syncthreads();
        for (int j = 0; j < m; ++j) {
            const int s   = srcs[j];
            const int eid = eids[j];
            float v = bc + P[(size_t)s * D_OUT + col];
            const float4* xe = (const float4*)(Xe + (size_t)eid * D_EDGE);
            #pragma unroll
            for (int kk = 0; kk < 8; ++kk) {
                const float4 x = xe[kk];
                v += x.x * we[4 * kk + 0];
                v += x.y * we[4 * kk + 1];
                v += x.z * we[4 * kk + 2];
                v += x.w * we[4 * kk + 3];
            }
            acc += fmaxf(v, 0.f);
        }
        __syncthreads();
    }
    H[(size_t)n * D_OUT + col] += acc;
}

// ---------------------------------------------------------------------------
// Fallback kernels (proven round-1 path) if workspace is too small.
// ---------------------------------------------------------------------------
__global__ __launch_bounds__(256) void edge_scatter(
    const float* __restrict__ P, const float* __restrict__ Xe,
    const float* __restrict__ We, const float* __restrict__ b,
    const int* __restrict__ src, const int* __restrict__ dst,
    float* __restrict__ H, int E)
{
    const int tid = threadIdx.x;
    const int col = tid & 127;
    const int sub = tid >> 7;
    float we[D_EDGE];
    #pragma unroll
    for (int k = 0; k < D_EDGE; ++k) we[k] = We[k * D_OUT + col];
    const float bc = b[col];
    const float4* Xe4 = (const float4*)Xe;
    const int slot = blockIdx.x * 2 + sub;
    const int nslots = gridDim.x * 2;
    for (int e = slot; e < E; e += nslots) {
        const int s = src[e];
        const int dt = dst[e];
        float acc = bc + P[(size_t)s * D_OUT + col];
        #pragma unroll
        for (int kk = 0; kk < 8; ++kk) {
            const float4 xv = Xe4[(size_t)e * 8 + kk];
            acc += xv.x * we[4 * kk + 0];
            acc += xv.y * we[4 * kk + 1];
            acc += xv.z * we[4 * kk + 2];
            acc += xv.w * we[4 * kk + 3];
        }
        acc = fmaxf(acc, 0.f);
        unsafeAtomicAdd(&H[(size_t)dt * D_OUT + col], acc);
    }
}

__global__ __launch_bounds__(256) void edge_scatter_fused(
    const float* __restrict__ Xsrc, const float* __restrict__ Wsrc,
    const float* __restrict__ Xe, const float* __restrict__ We,
    const float* __restrict__ b, const int* __restrict__ src,
    const int* __restrict__ dst, float* __restrict__ H, int E)
{
    __shared__ float Ws[D_IN * D_OUT];
    for (int i = threadIdx.x; i < D_IN * D_OUT; i += 256) Ws[i] = Wsrc[i];
    __syncthreads();
    const int tid = threadIdx.x;
    const int col = tid & 127;
    const int sub = tid >> 7;
    float we[D_EDGE];
    #pragma unroll
    for (int k = 0; k < D_EDGE; ++k) we[k] = We[k * D_OUT + col];
    const float bc = b[col];
    const float4* Xe4 = (const float4*)Xe;
    const int slot = blockIdx.x * 2 + sub;
    const int nslots = gridDim.x * 2;
    for (int e = slot; e < E; e += nslots) {
        const int s = src[e];
        const int dt = dst[e];
        float acc = bc;
        const float4* Xr4 = (const float4*)(Xsrc + (size_t)s * D_IN);
        #pragma unroll 8
        for (int k0 = 0; k0 < D_IN / 4; ++k0) {
            const float4 xv = Xr4[k0];
            acc += xv.x * Ws[(4 * k0 + 0) * D_OUT + col];
            acc += xv.y * Ws[(4 * k0 + 1) * D_OUT + col];
            acc += xv.z * Ws[(4 * k0 + 2) * D_OUT + col];
            acc += xv.w * Ws[(4 * k0 + 3) * D_OUT + col];
        }
        #pragma unroll
        for (int kk = 0; kk < 8; ++kk) {
            const float4 xv = Xe4[(size_t)e * 8 + kk];
            acc += xv.x * we[4 * kk + 0];
            acc += xv.y * we[4 * kk + 1];
            acc += xv.z * we[4 * kk + 2];
            acc += xv.w * we[4 * kk + 3];
        }
        acc = fmaxf(acc, 0.f);
        unsafeAtomicAdd(&H[(size_t)dt * D_OUT + col], acc);
    }
}

extern "C" void kernel_launch(void* const* d_in, const int* in_sizes, int n_in,
                              void* d_out, int out_size, void* d_ws, size_t ws_size,
                              hipStream_t stream)
{
    const float* X_user    = (const float*)d_in[0];
    const float* X_item    = (const float*)d_in[1];
    const float* Xe_ui     = (const float*)d_in[2];
    const float* Xe_iu     = (const float*)d_in[3];
    const float* W_src_ui  = (const float*)d_in[4];
    const float* W_edge_ui = (const float*)d_in[5];
    const float* b_ui      = (const float*)d_in[6];
    const float* W_src_iu  = (const float*)d_in[7];
    const float* W_edge_iu = (const float*)d_in[8];
    const float* b_iu      = (const float*)d_in[9];
    const float* Wl_user   = (const float*)d_in[10];
    const float* bl_user   = (const float*)d_in[11];
    const float* Wl_item   = (const float*)d_in[12];
    const float* bl_item   = (const float*)d_in[13];
    const int*   src_ui    = (const int*)d_in[14];
    const int*   dst_ui    = (const int*)d_in[15];
    const int*   src_iu    = (const int*)d_in[16];
    const int*   dst_iu    = (const int*)d_in[17];

    const int NU = in_sizes[0] / D_IN;
    const int NI = in_sizes[1] / D_IN;
    const int E  = in_sizes[14];

    float* H_user = (float*)d_out;
    float* H_item = H_user + (size_t)NU * D_OUT;

    // ---- workspace layout ----
    char*  base = (char*)d_ws;
    size_t wo   = 0;
    auto take = [&](size_t bytes) -> void* {
        void* p = base + wo;
        wo = (wo + bytes + 255) & ~(size_t)255;
        return p;
    };
    float* P_user    = (float*)take((size_t)NU * D_OUT * 4);
    float* P_item    = (float*)take((size_t)NI * D_OUT * 4);
    int*   sorted_ui = (int*)take((size_t)E * 4);
    int*   sorted_iu = (int*)take((size_t)E * 4);
    int*   offs_i    = (int*)take(((size_t)NI + 1) * 4);  // dst of ui = items
    int*   offs_u    = (int*)take(((size_t)NU + 1) * 4);  // dst of iu = users
    int*   cnt_i     = (int*)take(((size_t)NI + (size_t)NU) * 4);
    int*   cnt_u     = cnt_i + NI;
    const int nch_i  = (NI + 255) / 256;
    const int nch_u  = (NU + 255) / 256;
    int*   bsum_i    = (int*)take((size_t)nch_i * 4);
    int*   bsum_u    = (int*)take((size_t)nch_u * 4);
    const size_t need_sort = wo;
    const size_t need_P    = ((size_t)NU + (size_t)NI) * D_OUT * 4;

    const int ngrid_u = (NU + 63) / 64;
    const int ngrid_i = (NI + 63) / 64;

    if (ws_size >= need_sort && nch_i <= 512 && nch_u <= 512) {
        // ---- fast path: node GEMMs + counting sort + atomic-free gather ----
        node_transform<<<ngrid_u, 256, 0, stream>>>(
            X_user, W_src_ui, Wl_user, bl_user, P_user, H_user, NU);
        node_transform<<<ngrid_i, 256, 0, stream>>>(
            X_item, W_src_iu, Wl_item, bl_item, P_item, H_item, NI);

        hipMemsetAsync(cnt_i, 0, ((size_t)NI + (size_t)NU) * 4, stream);
        hist2<<<2048, 256, 0, stream>>>(dst_ui, dst_iu, cnt_i, cnt_u, E);

        scan1<<<nch_i, 256, 0, stream>>>(cnt_i, offs_i, bsum_i, NI);
        scan2<<<1, 512, 0, stream>>>(bsum_i, offs_i, NI, nch_i, E);
        scan3<<<nch_i, 256, 0, stream>>>(offs_i, bsum_i, NI);

        scan1<<<nch_u, 256, 0, stream>>>(cnt_u, offs_u, bsum_u, NU);
        scan2<<<1, 512, 0, stream>>>(bsum_u, offs_u, NU, nch_u, E);
        scan3<<<nch_u, 256, 0, stream>>>(offs_u, bsum_u, NU);

        scatter_sort<<<2048, 256, 0, stream>>>(dst_ui, offs_i, cnt_i, sorted_ui, E);
        scatter_sort<<<2048, 256, 0, stream>>>(dst_iu, offs_u, cnt_u, sorted_iu, E);

        aggregate<<<NI, 128, 0, stream>>>(
            P_user, Xe_ui, W_edge_ui, b_ui, src_ui, sorted_ui, offs_i, H_item, NI);
        aggregate<<<NU, 128, 0, stream>>>(
            P_item, Xe_iu, W_edge_iu, b_iu, src_iu, sorted_iu, offs_u, H_user, NU);
    } else if (ws_size >= need_P) {
        // ---- round-1 path: precomputed P + atomic scatter ----
        node_transform<<<ngrid_u, 256, 0, stream>>>(
            X_user, W_src_ui, Wl_user, bl_user, P_user, H_user, NU);
        node_transform<<<ngrid_i, 256, 0, stream>>>(
            X_item, W_src_iu, Wl_item, bl_item, P_item, H_item, NI);
        edge_scatter<<<8192, 256, 0, stream>>>(
            P_user, Xe_ui, W_edge_ui, b_ui, src_ui, dst_ui, H_item, E);
        edge_scatter<<<8192, 256, 0, stream>>>(
            P_item, Xe_iu, W_edge_iu, b_iu, src_iu, dst_iu, H_user, E);
    } else {
        // ---- no-workspace fallback ----
        node_transform<<<ngrid_u, 256, 0, stream>>>(
            X_user, Wl_user, Wl_user, bl_user, H_user, H_user, NU);
        node_transform<<<ngrid_i, 256, 0, stream>>>(
            X_item, Wl_item, Wl_item, bl_item, H_item, H_item, NI);
        edge_scatter_fused<<<8192, 256, 0, stream>>>(
            X_user, W_src_ui, Xe_ui, W_edge_ui, b_ui, src_ui, dst_ui, H_item, E);
        edge_scatter_fused<<<8192, 256, 0, stream>>>(
            X_item, W_src_iu, Xe_iu, W_edge_iu, b_iu, src_iu, dst_iu, H_user, E);
    }
}

// Round 5
// 1165.097 us; speedup vs baseline: 1.3527x; 1.0313x over previous
//
#include <hip/hip_runtime.h>
#include <hip/hip_bf16.h>

#define D_IN   128
#define D_EDGE 32
#define D_OUT  128

// ---------------------------------------------------------------------------
// Kernel 1: fused node transform (64 rows per block).
//   P[n,:]  = bf16( X[n,:] @ Wsrc )   (message precompute, to workspace)
//   Hi[n,:] = X[n,:] @ Wl + bl        (self-loop init of the output, f32)
// ---------------------------------------------------------------------------
__global__ __launch_bounds__(256) void node_transform(
    const float* __restrict__ X,
    const float* __restrict__ Wsrc,
    const float* __restrict__ Wl,
    const float* __restrict__ bl,
    __hip_bfloat16* __restrict__ P,
    float* __restrict__ Hi,
    int N)
{
    __shared__ float Xs[64 * D_IN];  // 32 KB
    const int tid  = threadIdx.x;
    const int row0 = blockIdx.x * 64;
    const int col  = tid & 127;
    const int q    = tid >> 7;

    const int rows = min(64, N - row0);
    if (rows == 64) {
        const float4* X4  = (const float4*)(X + (size_t)row0 * D_IN);
        float4*       Xs4 = (float4*)Xs;
        #pragma unroll
        for (int j = 0; j < 8; ++j) Xs4[tid + j * 256] = X4[tid + j * 256];
    } else {
        for (int i = tid; i < rows * D_IN; i += 256)
            Xs[i] = X[(size_t)row0 * D_IN + i];
        for (int i = rows * D_IN + tid; i < 64 * D_IN; i += 256)
            Xs[i] = 0.f;
    }
    __syncthreads();

    float accP[32], accL[32];
    #pragma unroll
    for (int r = 0; r < 32; ++r) { accP[r] = 0.f; accL[r] = 0.f; }

    for (int k0 = 0; k0 < D_IN; k0 += 4) {
        const float w0 = Wsrc[(k0 + 0) * D_OUT + col];
        const float w1 = Wsrc[(k0 + 1) * D_OUT + col];
        const float w2 = Wsrc[(k0 + 2) * D_OUT + col];
        const float w3 = Wsrc[(k0 + 3) * D_OUT + col];
        const float l0 = Wl[(k0 + 0) * D_OUT + col];
        const float l1 = Wl[(k0 + 1) * D_OUT + col];
        const float l2 = Wl[(k0 + 2) * D_OUT + col];
        const float l3 = Wl[(k0 + 3) * D_OUT + col];
        #pragma unroll
        for (int r = 0; r < 32; ++r) {
            const float4 x = *(const float4*)&Xs[(q * 32 + r) * D_IN + k0];
            accP[r] += x.x * w0 + x.y * w1 + x.z * w2 + x.w * w3;
            accL[r] += x.x * l0 + x.y * l1 + x.z * l2 + x.w * l3;
        }
    }

    const float blc = bl[col];
    #pragma unroll
    for (int r = 0; r < 32; ++r) {
        const int row = row0 + q * 32 + r;
        if (row < N) {
            P [(size_t)row * D_OUT + col] = __float2bfloat16(accP[r]);
            Hi[(size_t)row * D_OUT + col] = accL[r] + blc;
        }
    }
}

// ---------------------------------------------------------------------------
// Counting sort of edges by dst.
// ---------------------------------------------------------------------------
__global__ __launch_bounds__(256) void hist2(
    const int* __restrict__ dst_a, const int* __restrict__ dst_b,
    int* __restrict__ cnt_a, int* __restrict__ cnt_b, int E)
{
    const int i = blockIdx.x * 256 + threadIdx.x;
    const int n = gridDim.x * 256;
    for (int e = i; e < E; e += n) atomicAdd(&cnt_a[dst_a[e]], 1);
    for (int e = i; e < E; e += n) atomicAdd(&cnt_b[dst_b[e]], 1);
}

__global__ __launch_bounds__(256) void scan1(
    const int* __restrict__ cnt, int* __restrict__ offs,
    int* __restrict__ bsum, int N)
{
    __shared__ int s[256];
    const int i = blockIdx.x * 256 + threadIdx.x;
    const int v = (i < N) ? cnt[i] : 0;
    s[threadIdx.x] = v;
    __syncthreads();
    for (int d = 1; d < 256; d <<= 1) {
        const int t = (threadIdx.x >= d) ? s[threadIdx.x - d] : 0;
        __syncthreads();
        s[threadIdx.x] += t;
        __syncthreads();
    }
    const int incl = s[threadIdx.x];
    if (i < N) offs[i] = incl - v;
    if (threadIdx.x == 255) bsum[blockIdx.x] = incl;
}

__global__ __launch_bounds__(512) void scan2(
    int* __restrict__ bsum, int* __restrict__ offs, int N, int nch, int E)
{
    __shared__ int s[512];
    const int v = (threadIdx.x < nch) ? bsum[threadIdx.x] : 0;
    s[threadIdx.x] = v;
    __syncthreads();
    for (int d = 1; d < 512; d <<= 1) {
        const int t = (threadIdx.x >= d) ? s[threadIdx.x - d] : 0;
        __syncthreads();
        s[threadIdx.x] += t;
        __syncthreads();
    }
    if (threadIdx.x < nch) bsum[threadIdx.x] = s[threadIdx.x] - v;
    if (threadIdx.x == 0) offs[N] = E;
}

__global__ __launch_bounds__(256) void scan3(
    int* __restrict__ offs, const int* __restrict__ bsum, int N)
{
    const int i = blockIdx.x * 256 + threadIdx.x;
    if (i < N) offs[i] += bsum[blockIdx.x];
}

// Place (eid, src) pairs into dst-sorted order.
__global__ __launch_bounds__(256) void scatter_sort(
    const int* __restrict__ dst, const int* __restrict__ src,
    const int* __restrict__ offs, int* __restrict__ cnt,
    int2* __restrict__ sorted2, int E)
{
    const int i = blockIdx.x * 256 + threadIdx.x;
    const int n = gridDim.x * 256;
    for (int e = i; e < E; e += n) {
        const int d   = dst[e];
        const int s   = src[e];
        const int old = atomicSub(&cnt[d], 1);
        sorted2[offs[d] + old - 1] = make_int2(e, s);
    }
}

// ---------------------------------------------------------------------------
// Kernel 2: atomic-free aggregation, persistent blocks.
//   H[n,:] += sum_{e in edges(n)} relu(b + P[src[e],:] + Xe[e,:] @ We)
// we[] in registers for the block's lifetime; (eid,src) staged per chunk;
// j-loop unrolled x2 for memory-level parallelism on the random P gather.
// ---------------------------------------------------------------------------
__global__ __launch_bounds__(128) void aggregate(
    const __hip_bfloat16* __restrict__ P,  // [Nsrc, D_OUT] bf16
    const float* __restrict__ Xe,          // [E, D_EDGE]
    const float* __restrict__ We,           // [D_EDGE, D_OUT]
    const float* __restrict__ b,            // [D_OUT]
    const int2*  __restrict__ sorted2,      // [E] (eid, src) sorted by dst
    const int*   __restrict__ offs,         // [Ndst+1]
    float*       __restrict__ H,            // [Ndst, D_OUT]
    int N)
{
    const int col = threadIdx.x;
    float we[D_EDGE];
    #pragma unroll
    for (int k = 0; k < D_EDGE; ++k) we[k] = We[k * D_OUT + col];
    const float bc = b[col];

    __shared__ int2 es[128];
    const float4* Xe4 = (const float4*)Xe;

    for (int n = blockIdx.x; n < N; n += gridDim.x) {
        const int off = offs[n];
        const int deg = offs[n + 1] - off;
        if (deg == 0) continue;

        float acc = 0.f;
        for (int base = 0; base < deg; base += 128) {
            const int m = min(128, deg - base);
            if (col < m) es[col] = sorted2[off + base + col];
            __syncthreads();

            int j = 0;
            for (; j + 1 < m; j += 2) {
                const int2 e0 = es[j];
                const int2 e1 = es[j + 1];
                float v0 = bc + __bfloat162float(P[(size_t)e0.y * D_OUT + col]);
                float v1 = bc + __bfloat162float(P[(size_t)e1.y * D_OUT + col]);
                const float4* xe0 = &Xe4[(size_t)e0.x * 8];
                const float4* xe1 = &Xe4[(size_t)e1.x * 8];
                #pragma unroll
                for (int kk = 0; kk < 8; ++kk) {
                    const float4 x0 = xe0[kk];
                    const float4 x1 = xe1[kk];
                    v0 += x0.x * we[4 * kk + 0] + x0.y * we[4 * kk + 1]
                        + x0.z * we[4 * kk + 2] + x0.w * we[4 * kk + 3];
                    v1 += x1.x * we[4 * kk + 0] + x1.y * we[4 * kk + 1]
                        + x1.z * we[4 * kk + 2] + x1.w * we[4 * kk + 3];
                }
                acc += fmaxf(v0, 0.f) + fmaxf(v1, 0.f);
            }
            if (j < m) {
                const int2 e0 = es[j];
                float v0 = bc + __bfloat162float(P[(size_t)e0.y * D_OUT + col]);
                const float4* xe0 = &Xe4[(size_t)e0.x * 8];
                #pragma unroll
                for (int kk = 0; kk < 8; ++kk) {
                    const float4 x0 = xe0[kk];
                    v0 += x0.x * we[4 * kk + 0] + x0.y * we[4 * kk + 1]
                        + x0.z * we[4 * kk + 2] + x0.w * we[4 * kk + 3];
                }
                acc += fmaxf(v0, 0.f);
            }
            __syncthreads();
        }
        H[(size_t)n * D_OUT + col] += acc;
    }
}

// ---------------------------------------------------------------------------
// Fallback: atomic scatter with bf16 P (if sort workspace doesn't fit).
// ---------------------------------------------------------------------------
__global__ __launch_bounds__(256) void edge_scatter(
    const __hip_bfloat16* __restrict__ P, const float* __restrict__ Xe,
    const float* __restrict__ We, const float* __restrict__ b,
    const int* __restrict__ src, const int* __restrict__ dst,
    float* __restrict__ H, int E)
{
    const int tid = threadIdx.x;
    const int col = tid & 127;
    const int sub = tid >> 7;
    float we[D_EDGE];
    #pragma unroll
    for (int k = 0; k < D_EDGE; ++k) we[k] = We[k * D_OUT + col];
    const float bc = b[col];
    const float4* Xe4 = (const float4*)Xe;
    const int slot = blockIdx.x * 2 + sub;
    const int nslots = gridDim.x * 2;
    for (int e = slot; e < E; e += nslots) {
        const int s = src[e];
        const int dt = dst[e];
        float acc = bc + __bfloat162float(P[(size_t)s * D_OUT + col]);
        #pragma unroll
        for (int kk = 0; kk < 8; ++kk) {
            const float4 xv = Xe4[(size_t)e * 8 + kk];
            acc += xv.x * we[4 * kk + 0] + xv.y * we[4 * kk + 1]
                 + xv.z * we[4 * kk + 2] + xv.w * we[4 * kk + 3];
        }
        acc = fmaxf(acc, 0.f);
        unsafeAtomicAdd(&H[(size_t)dt * D_OUT + col], acc);
    }
}

extern "C" void kernel_launch(void* const* d_in, const int* in_sizes, int n_in,
                              void* d_out, int out_size, void* d_ws, size_t ws_size,
                              hipStream_t stream)
{
    const float* X_user    = (const float*)d_in[0];
    const float* X_item    = (const float*)d_in[1];
    const float* Xe_ui     = (const float*)d_in[2];
    const float* Xe_iu     = (const float*)d_in[3];
    const float* W_src_ui  = (const float*)d_in[4];
    const float* W_edge_ui = (const float*)d_in[5];
    const float* b_ui      = (const float*)d_in[6];
    const float* W_src_iu  = (const float*)d_in[7];
    const float* W_edge_iu = (const float*)d_in[8];
    const float* b_iu      = (const float*)d_in[9];
    const float* Wl_user   = (const float*)d_in[10];
    const float* bl_user   = (const float*)d_in[11];
    const float* Wl_item   = (const float*)d_in[12];
    const float* bl_item   = (const float*)d_in[13];
    const int*   src_ui    = (const int*)d_in[14];
    const int*   dst_ui    = (const int*)d_in[15];
    const int*   src_iu    = (const int*)d_in[16];
    const int*   dst_iu    = (const int*)d_in[17];

    const int NU = in_sizes[0] / D_IN;
    const int NI = in_sizes[1] / D_IN;
    const int E  = in_sizes[14];

    float* H_user = (float*)d_out;
    float* H_item = H_user + (size_t)NU * D_OUT;

    // ---- workspace layout ----
    char*  base = (char*)d_ws;
    size_t wo   = 0;
    auto take = [&](size_t bytes) -> void* {
        void* p = base + wo;
        wo = (wo + bytes + 255) & ~(size_t)255;
        return p;
    };
    __hip_bfloat16* P_user = (__hip_bfloat16*)take((size_t)NU * D_OUT * 2);
    __hip_bfloat16* P_item = (__hip_bfloat16*)take((size_t)NI * D_OUT * 2);
    int2* sorted_ui = (int2*)take((size_t)E * 8);
    int2* sorted_iu = (int2*)take((size_t)E * 8);
    int*  offs_i    = (int*)take(((size_t)NI + 1) * 4);  // dst of ui = items
    int*  offs_u    = (int*)take(((size_t)NU + 1) * 4);  // dst of iu = users
    int*  cnt_i     = (int*)take(((size_t)NI + (size_t)NU) * 4);
    int*  cnt_u     = cnt_i + NI;
    const int nch_i = (NI + 255) / 256;
    const int nch_u = (NU + 255) / 256;
    int*  bsum_i    = (int*)take((size_t)nch_i * 4);
    int*  bsum_u    = (int*)take((size_t)nch_u * 4);
    const size_t need_sort = wo;
    const size_t need_P    = ((size_t)NU + (size_t)NI) * D_OUT * 2;

    const int ngrid_u = (NU + 63) / 64;
    const int ngrid_i = (NI + 63) / 64;

    if (ws_size >= need_sort && nch_i <= 512 && nch_u <= 512) {
        // ---- fast path: node GEMMs + counting sort + atomic-free gather ----
        node_transform<<<ngrid_u, 256, 0, stream>>>(
            X_user, W_src_ui, Wl_user, bl_user, P_user, H_user, NU);
        node_transform<<<ngrid_i, 256, 0, stream>>>(
            X_item, W_src_iu, Wl_item, bl_item, P_item, H_item, NI);

        hipMemsetAsync(cnt_i, 0, ((size_t)NI + (size_t)NU) * 4, stream);
        hist2<<<2048, 256, 0, stream>>>(dst_ui, dst_iu, cnt_i, cnt_u, E);

        scan1<<<nch_i, 256, 0, stream>>>(cnt_i, offs_i, bsum_i, NI);
        scan2<<<1, 512, 0, stream>>>(bsum_i, offs_i, NI, nch_i, E);
        scan3<<<nch_i, 256, 0, stream>>>(offs_i, bsum_i, NI);

        scan1<<<nch_u, 256, 0, stream>>>(cnt_u, offs_u, bsum_u, NU);
        scan2<<<1, 512, 0, stream>>>(bsum_u, offs_u, NU, nch_u, E);
        scan3<<<nch_u, 256, 0, stream>>>(offs_u, bsum_u, NU);

        scatter_sort<<<2048, 256, 0, stream>>>(dst_ui, src_ui, offs_i, cnt_i, sorted_ui, E);
        scatter_sort<<<2048, 256, 0, stream>>>(dst_iu, src_iu, offs_u, cnt_u, sorted_iu, E);

        aggregate<<<4096, 128, 0, stream>>>(
            P_user, Xe_ui, W_edge_ui, b_ui, sorted_ui, offs_i, H_item, NI);
        aggregate<<<4096, 128, 0, stream>>>(
            P_item, Xe_iu, W_edge_iu, b_iu, sorted_iu, offs_u, H_user, NU);
    } else {
        // ---- fallback: precomputed bf16 P + atomic scatter ----
        node_transform<<<ngrid_u, 256, 0, stream>>>(
            X_user, W_src_ui, Wl_user, bl_user, P_user, H_user, NU);
        node_transform<<<ngrid_i, 256, 0, stream>>>(
            X_item, W_src_iu, Wl_item, bl_item, P_item, H_item, NI);
        edge_scatter<<<8192, 256, 0, stream>>>(
            P_user, Xe_ui, W_edge_ui, b_ui, src_ui, dst_ui, H_item, E);
        edge_scatter<<<8192, 256, 0, stream>>>(
            P_item, Xe_iu, W_edge_iu, b_iu, src_iu, dst_iu, H_user, E);
    }
}